// Round 1
// baseline (2151.623 us; speedup 1.0000x reference)
//
#include <hip/hip_runtime.h>
#include <math.h>

#define B_SZ 2
#define CDIM 256
#define NTOK 4096
#define NH 8
#define HD 32

// ---------------- transpose: src (B, C, N) -> dst (B, N, dst_ld) ----------------
__global__ __launch_bounds__(256) void transpose_kernel(
    const float* __restrict__ src, float* __restrict__ dst,
    int Cdim, int Ndim, int dst_ld) {
    __shared__ float tile[32][33];
    int tx = threadIdx.x & 31;
    int ty = threadIdx.x >> 5;  // 0..7
    int i0 = blockIdx.x * 32;
    int c0 = blockIdx.y * 32;
    int b = blockIdx.z;
    const float* s = src + (size_t)b * Cdim * Ndim;
    float* d = dst + (size_t)b * Ndim * dst_ld;
#pragma unroll
    for (int r = 0; r < 4; ++r) {
        int c = c0 + ty + r * 8;
        tile[ty + r * 8][tx] = s[(size_t)c * Ndim + i0 + tx];
    }
    __syncthreads();
#pragma unroll
    for (int r = 0; r < 4; ++r) {
        int i = i0 + ty + r * 8;
        d[(size_t)i * dst_ld + c0 + tx] = tile[tx][ty + r * 8];
    }
}

// ---------------- generic fp32 GEMM: C[M,N] = A[M,K](lda) @ W[K,N](ldw) ----------------
// OUT_MODE 0: plain row-major (ldc). OUT_MODE 1: QKV permute to (b, h, n_tok, hd).
template <int RELU, int OUT_MODE>
__global__ __launch_bounds__(256) void gemm_kernel(
    const float* __restrict__ A, int lda,
    const float* __restrict__ W, int ldw,
    const float* __restrict__ bias,
    float* __restrict__ C, int ldc, int K) {
    __shared__ float As[16][64];
    __shared__ float Bs[16][64];
    int tid = threadIdx.x;
    int m0 = blockIdx.x * 64;
    int n0 = blockIdx.y * 64;
    int arow = tid >> 2, ak = (tid & 3) * 4;    // A tile: 64 rows x 16 k
    int brow = tid >> 4, bn = (tid & 15) * 4;   // B tile: 16 k x 64 n
    int tm = (tid & 15) * 4;
    int tn = (tid >> 4) * 4;
    float acc[4][4] = {};
    for (int k0 = 0; k0 < K; k0 += 16) {
        float4 av = *(const float4*)&A[(size_t)(m0 + arow) * lda + k0 + ak];
        float4 bv = *(const float4*)&W[(size_t)(k0 + brow) * ldw + n0 + bn];
        As[ak + 0][arow] = av.x;
        As[ak + 1][arow] = av.y;
        As[ak + 2][arow] = av.z;
        As[ak + 3][arow] = av.w;
        *(float4*)&Bs[brow][bn] = bv;
        __syncthreads();
#pragma unroll
        for (int k = 0; k < 16; ++k) {
            float4 a4 = *(const float4*)&As[k][tm];
            float4 b4 = *(const float4*)&Bs[k][tn];
            float aa[4] = {a4.x, a4.y, a4.z, a4.w};
            float bb[4] = {b4.x, b4.y, b4.z, b4.w};
#pragma unroll
            for (int i = 0; i < 4; ++i)
#pragma unroll
                for (int j = 0; j < 4; ++j)
                    acc[i][j] = fmaf(aa[i], bb[j], acc[i][j]);
        }
        __syncthreads();
    }
#pragma unroll
    for (int i = 0; i < 4; ++i) {
        int m = m0 + tm + i;
#pragma unroll
        for (int j = 0; j < 4; ++j) {
            int n = n0 + tn + j;
            float v = acc[i][j];
            if (bias) v += bias[n];
            if (RELU) v = fmaxf(v, 0.f);
            if (OUT_MODE == 0) {
                C[(size_t)m * ldc + n] = v;
            } else {
                int b = m >> 12, itok = m & 4095;
                int h = n >> 5, dd = n & 31;
                C[(((size_t)b * NH + h) * NTOK + itok) * HD + dd] = v;
            }
        }
    }
}

// ---------------- flash attention (fp32), writes merged with the head-flatten permute ----
__global__ __launch_bounds__(256) void attn_kernel(
    const float* __restrict__ Q, const float* __restrict__ K,
    const float* __restrict__ V, float* __restrict__ merged) {
    __shared__ float Qs[64 * 32];
    __shared__ float Ks[64 * 32];
    __shared__ float Vs[64 * 32];
    int tid = threadIdx.x;
    int qt = blockIdx.x, h = blockIdx.y, b = blockIdx.z;
    size_t head_off = ((size_t)b * NH + h) * NTOK * HD;
    const float* Qb = Q + head_off + (size_t)qt * 64 * HD;
    const float* Kb = K + head_off;
    const float* Vb = V + head_off;
    for (int idx = tid; idx < 64 * 32; idx += 256) Qs[idx] = Qb[idx];
    __syncthreads();
    int ql = tid >> 2, quad = tid & 3;
    float qreg[32];
#pragma unroll
    for (int d = 0; d < 32; ++d) qreg[d] = Qs[ql * 32 + d];
    float m_run = -3.0e38f, l_run = 0.f;
    float o[32];
#pragma unroll
    for (int d = 0; d < 32; ++d) o[d] = 0.f;
    for (int kt = 0; kt < NTOK / 64; ++kt) {
        __syncthreads();
        for (int idx = tid; idx < 2048; idx += 256) {
            Ks[idx] = Kb[(size_t)kt * 2048 + idx];
            Vs[idx] = Vb[(size_t)kt * 2048 + idx];
        }
        __syncthreads();
        float s[16];
#pragma unroll
        for (int kk = 0; kk < 16; ++kk) {
            const float* kr = &Ks[(quad * 16 + kk) * 32];
            float acc = 0.f;
#pragma unroll
            for (int d = 0; d < 32; ++d) acc = fmaf(qreg[d], kr[d], acc);
            s[kk] = acc;
        }
        float tmax = s[0];
#pragma unroll
        for (int kk = 1; kk < 16; ++kk) tmax = fmaxf(tmax, s[kk]);
        tmax = fmaxf(tmax, __shfl_xor(tmax, 1));
        tmax = fmaxf(tmax, __shfl_xor(tmax, 2));
        float m_new = fmaxf(m_run, tmax);
        float alpha = __expf(m_run - m_new);
        float psum = 0.f;
#pragma unroll
        for (int kk = 0; kk < 16; ++kk) {
            s[kk] = __expf(s[kk] - m_new);
            psum += s[kk];
        }
        psum += __shfl_xor(psum, 1);
        psum += __shfl_xor(psum, 2);
        l_run = l_run * alpha + psum;
        m_run = m_new;
#pragma unroll
        for (int d = 0; d < 32; ++d) o[d] *= alpha;
#pragma unroll
        for (int kk = 0; kk < 16; ++kk) {
            const float* vr = &Vs[(quad * 16 + kk) * 32];
            float pk = s[kk];
#pragma unroll
            for (int d = 0; d < 32; ++d) o[d] = fmaf(pk, vr[d], o[d]);
        }
    }
#pragma unroll
    for (int d = 0; d < 32; ++d) {
        o[d] += __shfl_xor(o[d], 1);
        o[d] += __shfl_xor(o[d], 2);
    }
    float inv = 1.f / l_run;
    int q = qt * 64 + ql;
    // merged[b][h*512 + q>>3][(q&7)*32 + d]  (faithful head-flatten without transpose)
    size_t base = ((size_t)b * NTOK + h * 512 + (q >> 3)) * 256 + (q & 7) * 32;
#pragma unroll
    for (int j = 0; j < 8; ++j) {
        int d = quad * 8 + j;
        merged[base + d] = o[d] * inv;
    }
}

// ---------------- layernorm over 256, one wave per row; optional residual add ---------
__global__ __launch_bounds__(256) void ln_kernel(
    const float* __restrict__ src, int src_ld,
    const float* __restrict__ gamma, const float* __restrict__ beta,
    float* __restrict__ dst, int dst_ld, int dst_off,
    const float* __restrict__ resid, int resid_ld) {
    int lane = threadIdx.x & 63;
    int wv = threadIdx.x >> 6;
    int row = blockIdx.x * 4 + wv;
    const float* p = src + (size_t)row * src_ld;
    float4 v4 = *(const float4*)&p[lane * 4];
    float vv[4] = {v4.x, v4.y, v4.z, v4.w};
    float sum = vv[0] + vv[1] + vv[2] + vv[3];
#pragma unroll
    for (int off = 32; off >= 1; off >>= 1) sum += __shfl_xor(sum, off);
    float mu = sum * (1.f / 256.f);
    float vs = 0.f;
#pragma unroll
    for (int j = 0; j < 4; ++j) {
        float dxe = vv[j] - mu;
        vs += dxe * dxe;
    }
#pragma unroll
    for (int off = 32; off >= 1; off >>= 1) vs += __shfl_xor(vs, off);
    float rs = rsqrtf(vs * (1.f / 256.f) + 1e-5f);
    float* dp = dst + (size_t)row * dst_ld + dst_off;
    const float* rp = resid ? resid + (size_t)row * resid_ld : nullptr;
#pragma unroll
    for (int j = 0; j < 4; ++j) {
        int c = lane * 4 + j;
        float val = (vv[j] - mu) * rs * gamma[c] + beta[c];
        if (rp) val += rp[c];
        dp[c] = val;
    }
}

extern "C" void kernel_launch(void* const* d_in, const int* in_sizes, int n_in,
                              void* d_out, int out_size, void* d_ws, size_t ws_size,
                              hipStream_t stream) {
    const float* x = (const float*)d_in[0];
    const float* source = (const float*)d_in[1];
    const float* Wq = (const float*)d_in[2];
    const float* bq = (const float*)d_in[3];
    const float* Wk = (const float*)d_in[4];
    const float* bk = (const float*)d_in[5];
    const float* Wv = (const float*)d_in[6];
    const float* bv = (const float*)d_in[7];
    const float* Wm = (const float*)d_in[8];
    const float* Wmlp1 = (const float*)d_in[9];
    const float* Wmlp2 = (const float*)d_in[10];
    const float* g1 = (const float*)d_in[11];
    const float* b1 = (const float*)d_in[12];
    const float* g2 = (const float*)d_in[13];
    const float* b2 = (const float*)d_in[14];
    float* out = (float*)d_out;
    float* ws = (float*)d_ws;

    // workspace layout (floats):
    float* C0 = ws;                  // (2,4096,512): [:, :, 0:256]=xt, [:, :, 256:512]=a
    float* st = ws + 4194304;        // (2,4096,256)
    float* Qp = ws + 6291456;        // (2,8,4096,32)
    float* Kp = ws + 8388608;
    float* Vp = ws + 10485760;
    float* merged = st;              // reuse st after K/V projections
    float* t1 = Qp;                  // reuse Qp after attention
    float* t2 = Kp;                  // (2,4096,512) spans Kp+Vp after attention
    float* t3 = st;                  // reuse merged region after t1 GEMM

    // 1. transposes: x -> C0 lower half (ld 512), source -> st (ld 256)
    transpose_kernel<<<dim3(NTOK / 32, CDIM / 32, B_SZ), 256, 0, stream>>>(x, C0, CDIM, NTOK, 512);
    transpose_kernel<<<dim3(NTOK / 32, CDIM / 32, B_SZ), 256, 0, stream>>>(source, st, CDIM, NTOK, 256);

    // 2. Q/K/V projections (output permuted to (b,h,n,hd))
    dim3 g256(8192 / 64, 256 / 64);
    gemm_kernel<0, 1><<<g256, 256, 0, stream>>>(C0, 512, Wq, 256, bq, Qp, 0, 256);
    gemm_kernel<0, 1><<<g256, 256, 0, stream>>>(st, 256, Wk, 256, bk, Kp, 0, 256);
    gemm_kernel<0, 1><<<g256, 256, 0, stream>>>(st, 256, Wv, 256, bv, Vp, 0, 256);

    // 3. flash attention -> merged (with head-flatten permute)
    attn_kernel<<<dim3(NTOK / 64, NH, B_SZ), 256, 0, stream>>>(Qp, Kp, Vp, merged);

    // 4. merged @ Wm -> t1
    gemm_kernel<0, 0><<<g256, 256, 0, stream>>>(merged, 256, Wm, 256, nullptr, t1, 256, 256);

    // 5. LN1 -> C0 upper half
    ln_kernel<<<2048, 256, 0, stream>>>(t1, 256, g1, b1, C0, 512, 256, nullptr, 0);

    // 6. MLP1 with ReLU: C0 (8192x512) @ Wmlp1 (512x512) -> t2
    gemm_kernel<1, 0><<<dim3(8192 / 64, 512 / 64), 256, 0, stream>>>(C0, 512, Wmlp1, 512, nullptr, t2, 512, 512);

    // 7. MLP2: t2 @ Wmlp2 (512x256) -> t3
    gemm_kernel<0, 0><<<g256, 256, 0, stream>>>(t2, 512, Wmlp2, 256, nullptr, t3, 256, 512);

    // 8. LN2 + residual(xt) -> out
    ln_kernel<<<2048, 256, 0, stream>>>(t3, 256, g2, b2, out, 256, 0, C0, 512);
}

// Round 3
// 463.838 us; speedup vs baseline: 4.6387x; 4.6387x over previous
//
#include <hip/hip_runtime.h>
#include <math.h>

#define B_SZ 2
#define CDIM 256
#define NTOK 4096
#define NH 8
#define HD 32

typedef __attribute__((ext_vector_type(8))) short short8;
typedef __attribute__((ext_vector_type(4))) float f32x4;

static __device__ __forceinline__ short f2bf(float f) {
    unsigned int u = __builtin_bit_cast(unsigned int, f);
    u = u + 0x7fffu + ((u >> 16) & 1u);
    return (short)(u >> 16);
}

// ---------------- transpose: src (B, C, N) -> dst (B, N, dst_ld) ----------------
__global__ __launch_bounds__(256) void transpose_kernel(
    const float* __restrict__ src, float* __restrict__ dst,
    int Cdim, int Ndim, int dst_ld) {
    __shared__ float tile[32][33];
    int tx = threadIdx.x & 31;
    int ty = threadIdx.x >> 5;  // 0..7
    int i0 = blockIdx.x * 32;
    int c0 = blockIdx.y * 32;
    int b = blockIdx.z;
    const float* s = src + (size_t)b * Cdim * Ndim;
    float* d = dst + (size_t)b * Ndim * dst_ld;
#pragma unroll
    for (int r = 0; r < 4; ++r) {
        int c = c0 + ty + r * 8;
        tile[ty + r * 8][tx] = s[(size_t)c * Ndim + i0 + tx];
    }
    __syncthreads();
#pragma unroll
    for (int r = 0; r < 4; ++r) {
        int i = i0 + ty + r * 8;
        d[(size_t)i * dst_ld + c0 + tx] = tile[tx][ty + r * 8];
    }
}

// ---------------- generic fp32 GEMM: C[M,N] = A[M,K](lda) @ W[K,N](ldw) ----------------
// OUT_MODE 0: plain row-major fp32 (ldc).
// OUT_MODE 1: bf16, permute to (b, h, n_tok, hd)      [Q, K]
// OUT_MODE 2: bf16, permute to (b, h, hd, n_tok)      [V transposed]
template <int RELU, int OUT_MODE>
__global__ __launch_bounds__(256) void gemm_kernel(
    const float* __restrict__ A, int lda,
    const float* __restrict__ W, int ldw,
    const float* __restrict__ bias,
    void* __restrict__ Cv, int ldc, int K) {
    __shared__ float As[16][64];
    __shared__ float Bs[16][64];
    int tid = threadIdx.x;
    int m0 = blockIdx.x * 64;
    int n0 = blockIdx.y * 64;
    int arow = tid >> 2, ak = (tid & 3) * 4;    // A tile: 64 rows x 16 k
    int brow = tid >> 4, bn = (tid & 15) * 4;   // B tile: 16 k x 64 n
    int tm = (tid & 15) * 4;
    int tn = (tid >> 4) * 4;
    float acc[4][4] = {};
    for (int k0 = 0; k0 < K; k0 += 16) {
        float4 av = *(const float4*)&A[(size_t)(m0 + arow) * lda + k0 + ak];
        float4 bv = *(const float4*)&W[(size_t)(k0 + brow) * ldw + n0 + bn];
        As[ak + 0][arow] = av.x;
        As[ak + 1][arow] = av.y;
        As[ak + 2][arow] = av.z;
        As[ak + 3][arow] = av.w;
        *(float4*)&Bs[brow][bn] = bv;
        __syncthreads();
#pragma unroll
        for (int k = 0; k < 16; ++k) {
            float4 a4 = *(const float4*)&As[k][tm];
            float4 b4 = *(const float4*)&Bs[k][tn];
            float aa[4] = {a4.x, a4.y, a4.z, a4.w};
            float bb[4] = {b4.x, b4.y, b4.z, b4.w};
#pragma unroll
            for (int i = 0; i < 4; ++i)
#pragma unroll
                for (int j = 0; j < 4; ++j)
                    acc[i][j] = fmaf(aa[i], bb[j], acc[i][j]);
        }
        __syncthreads();
    }
#pragma unroll
    for (int i = 0; i < 4; ++i) {
        int m = m0 + tm + i;
#pragma unroll
        for (int j = 0; j < 4; ++j) {
            int n = n0 + tn + j;
            float v = acc[i][j];
            if (bias) v += bias[n];
            if (RELU) v = fmaxf(v, 0.f);
            if (OUT_MODE == 0) {
                ((float*)Cv)[(size_t)m * ldc + n] = v;
            } else if (OUT_MODE == 1) {
                int b = m >> 12, itok = m & 4095;
                int h = n >> 5, dd = n & 31;
                ((unsigned short*)Cv)[(((size_t)b * NH + h) * NTOK + itok) * HD + dd] = (unsigned short)f2bf(v);
            } else {
                int b = m >> 12, itok = m & 4095;
                int h = n >> 5, dd = n & 31;
                ((unsigned short*)Cv)[(((size_t)b * NH + h) * HD + dd) * NTOK + itok] = (unsigned short)f2bf(v);
            }
        }
    }
}

// ---------------- MFMA flash attention (bf16 in, fp32 accum) ----------------
// Q,K: (b, h, ntok, 32) bf16.  VT: (b, h, 32, ntok) bf16.
// 4 waves/block, wave w owns queries [qt*64 + w*16, +16).
// merged written with the faithful head-flatten permute.
__global__ __launch_bounds__(256) void attn_kernel(
    const unsigned short* __restrict__ Q, const unsigned short* __restrict__ K,
    const unsigned short* __restrict__ VT, float* __restrict__ merged) {
    __shared__ __align__(16) short Ps[4][16][72];  // per-wave P tile, padded stride
    int tid = threadIdx.x;
    int w = tid >> 6;
    int l = tid & 63;
    int lg = l >> 4;   // 0..3 (k-group)
    int lc = l & 15;   // 0..15 (row/col within fragment)
    int qt = blockIdx.x, h = blockIdx.y, b = blockIdx.z;
    size_t head_off = ((size_t)b * NH + h) * NTOK * HD;
    const unsigned short* Qb = Q + head_off;
    const unsigned short* Kb = K + head_off;
    const unsigned short* Vb = VT + head_off;  // (32, NTOK)

    // Q fragment: A[row=lc][k=lg*8+i]
    short8 qf = *(const short8*)&Qb[(size_t)(qt * 64 + w * 16 + lc) * HD + lg * 8];

    f32x4 zero = {0.f, 0.f, 0.f, 0.f};
    f32x4 oacc[2];
    oacc[0] = zero;
    oacc[1] = zero;
    float m_run[4], l_run[4];
#pragma unroll
    for (int r = 0; r < 4; ++r) { m_run[r] = -3.0e38f; l_run[r] = 0.f; }

    for (int kv = 0; kv < NTOK / 64; ++kv) {
        // ---- scores: S[16q x 64k], 4 MFMAs ----
        f32x4 sacc[4];
#pragma unroll
        for (int kt = 0; kt < 4; ++kt) {
            short8 kf = *(const short8*)&Kb[(size_t)(kv * 64 + kt * 16 + lc) * HD + lg * 8];
            sacc[kt] = __builtin_amdgcn_mfma_f32_16x16x32_bf16(qf, kf, zero, 0, 0, 0);
        }
        // ---- online softmax; D layout: row = lg*4+r, col(key) = lc ----
        float alpha[4];
#pragma unroll
        for (int r = 0; r < 4; ++r) {
            float t = fmaxf(fmaxf(sacc[0][r], sacc[1][r]), fmaxf(sacc[2][r], sacc[3][r]));
            t = fmaxf(t, __shfl_xor(t, 1));
            t = fmaxf(t, __shfl_xor(t, 2));
            t = fmaxf(t, __shfl_xor(t, 4));
            t = fmaxf(t, __shfl_xor(t, 8));
            float m_new = fmaxf(m_run[r], t);
            alpha[r] = __expf(m_run[r] - m_new);
            m_run[r] = m_new;
            float ps = 0.f;
#pragma unroll
            for (int kt = 0; kt < 4; ++kt) {
                float p = __expf(sacc[kt][r] - m_new);
                sacc[kt][r] = p;
                ps += p;
            }
            ps += __shfl_xor(ps, 1);
            ps += __shfl_xor(ps, 2);
            ps += __shfl_xor(ps, 4);
            ps += __shfl_xor(ps, 8);
            l_run[r] = l_run[r] * alpha[r] + ps;
        }
        // ---- P -> LDS (bf16), re-layout to A-operand pattern ----
#pragma unroll
        for (int kt = 0; kt < 4; ++kt)
#pragma unroll
            for (int r = 0; r < 4; ++r)
                Ps[w][lg * 4 + r][kt * 16 + lc] = f2bf(sacc[kt][r]);
        // ---- rescale O ----
#pragma unroll
        for (int dt = 0; dt < 2; ++dt)
#pragma unroll
            for (int r = 0; r < 4; ++r)
                oacc[dt][r] *= alpha[r];
        // ---- PV: O[16q x 32d] += P[16 x 64] @ V[64 x 32] ----
#pragma unroll
        for (int ktile = 0; ktile < 2; ++ktile) {
            short8 pf = *(const short8*)&Ps[w][lc][ktile * 32 + lg * 8];
#pragma unroll
            for (int dt = 0; dt < 2; ++dt) {
                short8 vf = *(const short8*)&Vb[(size_t)(dt * 16 + lc) * NTOK + kv * 64 + ktile * 32 + lg * 8];
                oacc[dt] = __builtin_amdgcn_mfma_f32_16x16x32_bf16(pf, vf, oacc[dt], 0, 0, 0);
            }
        }
    }
    // ---- epilogue: merged[b][h*512 + q>>3][(q&7)*32 + d] ----
#pragma unroll
    for (int r = 0; r < 4; ++r) {
        float inv = 1.f / l_run[r];
        int q = qt * 64 + w * 16 + lg * 4 + r;
        size_t base = ((size_t)b * NTOK + h * 512 + (q >> 3)) * 256 + (q & 7) * 32;
#pragma unroll
        for (int dt = 0; dt < 2; ++dt)
            merged[base + dt * 16 + lc] = oacc[dt][r] * inv;
    }
}

// ---------------- layernorm over 256, one wave per row; optional residual add ---------
__global__ __launch_bounds__(256) void ln_kernel(
    const float* __restrict__ src, int src_ld,
    const float* __restrict__ gamma, const float* __restrict__ beta,
    float* __restrict__ dst, int dst_ld, int dst_off,
    const float* __restrict__ resid, int resid_ld) {
    int lane = threadIdx.x & 63;
    int wv = threadIdx.x >> 6;
    int row = blockIdx.x * 4 + wv;
    const float* p = src + (size_t)row * src_ld;
    float4 v4 = *(const float4*)&p[lane * 4];
    float vv[4] = {v4.x, v4.y, v4.z, v4.w};
    float sum = vv[0] + vv[1] + vv[2] + vv[3];
#pragma unroll
    for (int off = 32; off >= 1; off >>= 1) sum += __shfl_xor(sum, off);
    float mu = sum * (1.f / 256.f);
    float vs = 0.f;
#pragma unroll
    for (int j = 0; j < 4; ++j) {
        float dxe = vv[j] - mu;
        vs += dxe * dxe;
    }
#pragma unroll
    for (int off = 32; off >= 1; off >>= 1) vs += __shfl_xor(vs, off);
    float rs = rsqrtf(vs * (1.f / 256.f) + 1e-5f);
    float* dp = dst + (size_t)row * dst_ld + dst_off;
    const float* rp = resid ? resid + (size_t)row * resid_ld : nullptr;
#pragma unroll
    for (int j = 0; j < 4; ++j) {
        int c = lane * 4 + j;
        float val = (vv[j] - mu) * rs * gamma[c] + beta[c];
        if (rp) val += rp[c];
        dp[c] = val;
    }
}

extern "C" void kernel_launch(void* const* d_in, const int* in_sizes, int n_in,
                              void* d_out, int out_size, void* d_ws, size_t ws_size,
                              hipStream_t stream) {
    const float* x = (const float*)d_in[0];
    const float* source = (const float*)d_in[1];
    const float* Wq = (const float*)d_in[2];
    const float* bq = (const float*)d_in[3];
    const float* Wk = (const float*)d_in[4];
    const float* bk = (const float*)d_in[5];
    const float* Wv = (const float*)d_in[6];
    const float* bv = (const float*)d_in[7];
    const float* Wm = (const float*)d_in[8];
    const float* Wmlp1 = (const float*)d_in[9];
    const float* Wmlp2 = (const float*)d_in[10];
    const float* g1 = (const float*)d_in[11];
    const float* b1 = (const float*)d_in[12];
    const float* g2 = (const float*)d_in[13];
    const float* b2 = (const float*)d_in[14];
    float* out = (float*)d_out;
    float* ws = (float*)d_ws;

    // workspace layout (float offsets):
    float* C0 = ws;                         // (2,4096,512): [:,:,0:256]=xt, [:,:,256:512]=a
    float* st = ws + 4194304;               // (2,4096,256)
    unsigned short* Qb = (unsigned short*)(ws + 6291456);   // bf16 (2,8,4096,32)
    unsigned short* Kb = (unsigned short*)(ws + 8388608);   // bf16 (2,8,4096,32)
    unsigned short* Vt = (unsigned short*)(ws + 10485760);  // bf16 (2,8,32,4096)
    float* merged = st;                     // reuse st after K/V projections
    float* t1 = ws + 6291456;               // reuse Q region after attention
    float* t2 = ws + 8388608;               // (2,4096,512) spans K+V regions
    float* t3 = st;                         // reuse merged region

    // 1. transposes
    transpose_kernel<<<dim3(NTOK / 32, CDIM / 32, B_SZ), 256, 0, stream>>>(x, C0, CDIM, NTOK, 512);
    transpose_kernel<<<dim3(NTOK / 32, CDIM / 32, B_SZ), 256, 0, stream>>>(source, st, CDIM, NTOK, 256);

    // 2. Q/K/V projections -> bf16, head-major (V transposed)
    dim3 g256(8192 / 64, 256 / 64);
    gemm_kernel<0, 1><<<g256, 256, 0, stream>>>(C0, 512, Wq, 256, bq, Qb, 0, 256);
    gemm_kernel<0, 1><<<g256, 256, 0, stream>>>(st, 256, Wk, 256, bk, Kb, 0, 256);
    gemm_kernel<0, 2><<<g256, 256, 0, stream>>>(st, 256, Wv, 256, bv, Vt, 0, 256);

    // 3. MFMA flash attention -> merged (head-flatten permute)
    attn_kernel<<<dim3(NTOK / 64, NH, B_SZ), 256, 0, stream>>>(Qb, Kb, Vt, merged);

    // 4. merged @ Wm -> t1
    gemm_kernel<0, 0><<<g256, 256, 0, stream>>>(merged, 256, Wm, 256, nullptr, t1, 256, 256);

    // 5. LN1 -> C0 upper half
    ln_kernel<<<2048, 256, 0, stream>>>(t1, 256, g1, b1, C0, 512, 256, nullptr, 0);

    // 6. MLP1 with ReLU: C0 (8192x512) @ Wmlp1 (512x512) -> t2
    gemm_kernel<1, 0><<<dim3(8192 / 64, 512 / 64), 256, 0, stream>>>(C0, 512, Wmlp1, 512, nullptr, t2, 512, 512);

    // 7. MLP2: t2 @ Wmlp2 (512x256) -> t3
    gemm_kernel<0, 0><<<g256, 256, 0, stream>>>(t2, 512, Wmlp2, 256, nullptr, t3, 256, 512);

    // 8. LN2 + residual(xt) -> out
    ln_kernel<<<2048, 256, 0, stream>>>(t3, 256, g2, b2, out, 256, 0, C0, 512);
}

// Round 4
// 406.636 us; speedup vs baseline: 5.2913x; 1.1407x over previous
//
#include <hip/hip_runtime.h>
#include <math.h>

#define B_SZ 2
#define CDIM 256
#define NTOK 4096
#define NH 8
#define HD 32

typedef __attribute__((ext_vector_type(8))) short short8;
typedef __attribute__((ext_vector_type(4))) float f32x4;

static __device__ __forceinline__ unsigned short f2bf(float f) {
    unsigned int u = __builtin_bit_cast(unsigned int, f);
    u = u + 0x7fffu + ((u >> 16) & 1u);
    return (unsigned short)(u >> 16);
}
static __device__ __forceinline__ float bf2f(unsigned short u) {
    unsigned int x = ((unsigned int)u) << 16;
    return __builtin_bit_cast(float, x);
}

// ------- transpose+bf16: src (B, C, N) fp32 -> dst (B, N, dst_ld) bf16 -------
// Also used for weight transposes (B=1): W (K,N) -> W^T (N,K).
__global__ __launch_bounds__(256) void transpose_bf_kernel(
    const float* __restrict__ src, unsigned short* __restrict__ dst,
    int Cdim, int Ndim, int dst_ld) {
    __shared__ float tile[32][33];
    int tx = threadIdx.x & 31;
    int ty = threadIdx.x >> 5;  // 0..7
    int i0 = blockIdx.x * 32;
    int c0 = blockIdx.y * 32;
    int b = blockIdx.z;
    const float* s = src + (size_t)b * Cdim * Ndim;
    unsigned short* d = dst + (size_t)b * Ndim * dst_ld;
#pragma unroll
    for (int r = 0; r < 4; ++r) {
        int c = c0 + ty + r * 8;
        tile[ty + r * 8][tx] = s[(size_t)c * Ndim + i0 + tx];
    }
    __syncthreads();
#pragma unroll
    for (int r = 0; r < 4; ++r) {
        int i = i0 + ty + r * 8;
        d[(size_t)i * dst_ld + c0 + tx] = f2bf(tile[tx][ty + r * 8]);
    }
}

// ------------- bf16 MFMA GEMM: C[M,N] = A[M,K](lda) @ BT[N,K]^T + bias -------------
// A: bf16 row-major (lda). BT: bf16 (N,K) row-major (W^T), ld = K.
// 4 waves/block; wave w computes rows [bx*64+w*16, +16) x cols [by*64, +64).
// OUT_MODE 0: fp32 row-major (ldc). 1: bf16 QKV permute (b,h,n,hd).
// 2: bf16 V^T permute (b,h,hd,n). 3: bf16 row-major (ldc).
template <int RELU, int OUT_MODE>
__global__ __launch_bounds__(256) void bgemm_kernel(
    const unsigned short* __restrict__ A, int lda,
    const unsigned short* __restrict__ BT,
    const float* __restrict__ bias,
    void* __restrict__ Cv, int ldc, int K) {
    int tid = threadIdx.x;
    int w = tid >> 6;
    int l = tid & 63;
    int lg = l >> 4;   // 0..3
    int lc = l & 15;   // 0..15
    int m0 = blockIdx.x * 64 + w * 16;
    int n0 = blockIdx.y * 64;
    const unsigned short* arow = A + (size_t)(m0 + lc) * lda;
    f32x4 acc[4];
    f32x4 zero = {0.f, 0.f, 0.f, 0.f};
#pragma unroll
    for (int nt = 0; nt < 4; ++nt) acc[nt] = zero;
#pragma unroll 4
    for (int k0 = 0; k0 < K; k0 += 32) {
        short8 af = *(const short8*)&arow[k0 + lg * 8];
#pragma unroll
        for (int nt = 0; nt < 4; ++nt) {
            short8 bf = *(const short8*)&BT[(size_t)(n0 + nt * 16 + lc) * K + k0 + lg * 8];
            acc[nt] = __builtin_amdgcn_mfma_f32_16x16x32_bf16(af, bf, acc[nt], 0, 0, 0);
        }
    }
#pragma unroll
    for (int nt = 0; nt < 4; ++nt) {
#pragma unroll
        for (int r = 0; r < 4; ++r) {
            int m = m0 + lg * 4 + r;
            int n = n0 + nt * 16 + lc;
            float v = acc[nt][r];
            if (bias) v += bias[n];
            if (RELU) v = fmaxf(v, 0.f);
            if (OUT_MODE == 0) {
                ((float*)Cv)[(size_t)m * ldc + n] = v;
            } else if (OUT_MODE == 1) {
                int b = m >> 12, itok = m & 4095;
                int h = n >> 5, dd = n & 31;
                ((unsigned short*)Cv)[(((size_t)b * NH + h) * NTOK + itok) * HD + dd] = f2bf(v);
            } else if (OUT_MODE == 2) {
                int b = m >> 12, itok = m & 4095;
                int h = n >> 5, dd = n & 31;
                ((unsigned short*)Cv)[(((size_t)b * NH + h) * HD + dd) * NTOK + itok] = f2bf(v);
            } else {
                ((unsigned short*)Cv)[(size_t)m * ldc + n] = f2bf(v);
            }
        }
    }
}

// ---------------- MFMA flash attention (bf16 in, fp32 accum) ----------------
// Q,K: (b, h, ntok, 32) bf16.  VT: (b, h, 32, ntok) bf16.
// 4 waves/block, wave w owns queries [qt*64 + w*16, +16).
// merged written bf16 with the faithful head-flatten permute.
__global__ __launch_bounds__(256) void attn_kernel(
    const unsigned short* __restrict__ Q, const unsigned short* __restrict__ K,
    const unsigned short* __restrict__ VT, unsigned short* __restrict__ merged) {
    __shared__ __align__(16) short Ps[4][16][72];  // per-wave P tile, padded stride
    int tid = threadIdx.x;
    int w = tid >> 6;
    int l = tid & 63;
    int lg = l >> 4;   // 0..3 (k-group)
    int lc = l & 15;   // 0..15 (row/col within fragment)
    int qt = blockIdx.x, h = blockIdx.y, b = blockIdx.z;
    size_t head_off = ((size_t)b * NH + h) * NTOK * HD;
    const unsigned short* Qb = Q + head_off;
    const unsigned short* Kb = K + head_off;
    const unsigned short* Vb = VT + head_off;  // (32, NTOK)

    // Q fragment: A[row=lc][k=lg*8+i]
    short8 qf = *(const short8*)&Qb[(size_t)(qt * 64 + w * 16 + lc) * HD + lg * 8];

    f32x4 zero = {0.f, 0.f, 0.f, 0.f};
    f32x4 oacc[2];
    oacc[0] = zero;
    oacc[1] = zero;
    float m_run[4], l_run[4];
#pragma unroll
    for (int r = 0; r < 4; ++r) { m_run[r] = -3.0e38f; l_run[r] = 0.f; }

    for (int kv = 0; kv < NTOK / 64; ++kv) {
        // ---- scores: S[16q x 64k], 4 MFMAs ----
        f32x4 sacc[4];
#pragma unroll
        for (int kt = 0; kt < 4; ++kt) {
            short8 kf = *(const short8*)&Kb[(size_t)(kv * 64 + kt * 16 + lc) * HD + lg * 8];
            sacc[kt] = __builtin_amdgcn_mfma_f32_16x16x32_bf16(qf, kf, zero, 0, 0, 0);
        }
        // ---- online softmax; D layout: row = lg*4+r, col(key) = lc ----
        float alpha[4];
#pragma unroll
        for (int r = 0; r < 4; ++r) {
            float t = fmaxf(fmaxf(sacc[0][r], sacc[1][r]), fmaxf(sacc[2][r], sacc[3][r]));
            t = fmaxf(t, __shfl_xor(t, 1));
            t = fmaxf(t, __shfl_xor(t, 2));
            t = fmaxf(t, __shfl_xor(t, 4));
            t = fmaxf(t, __shfl_xor(t, 8));
            float m_new = fmaxf(m_run[r], t);
            alpha[r] = __expf(m_run[r] - m_new);
            m_run[r] = m_new;
            float ps = 0.f;
#pragma unroll
            for (int kt = 0; kt < 4; ++kt) {
                float p = __expf(sacc[kt][r] - m_new);
                sacc[kt][r] = p;
                ps += p;
            }
            ps += __shfl_xor(ps, 1);
            ps += __shfl_xor(ps, 2);
            ps += __shfl_xor(ps, 4);
            ps += __shfl_xor(ps, 8);
            l_run[r] = l_run[r] * alpha[r] + ps;
        }
        // ---- P -> LDS (bf16), re-layout to A-operand pattern ----
#pragma unroll
        for (int kt = 0; kt < 4; ++kt)
#pragma unroll
            for (int r = 0; r < 4; ++r)
                Ps[w][lg * 4 + r][kt * 16 + lc] = (short)f2bf(sacc[kt][r]);
        // ---- rescale O ----
#pragma unroll
        for (int dt = 0; dt < 2; ++dt)
#pragma unroll
            for (int r = 0; r < 4; ++r)
                oacc[dt][r] *= alpha[r];
        // ---- PV: O[16q x 32d] += P[16 x 64] @ V[64 x 32] ----
#pragma unroll
        for (int ktile = 0; ktile < 2; ++ktile) {
            short8 pf = *(const short8*)&Ps[w][lc][ktile * 32 + lg * 8];
#pragma unroll
            for (int dt = 0; dt < 2; ++dt) {
                short8 vf = *(const short8*)&Vb[(size_t)(dt * 16 + lc) * NTOK + kv * 64 + ktile * 32 + lg * 8];
                oacc[dt] = __builtin_amdgcn_mfma_f32_16x16x32_bf16(pf, vf, oacc[dt], 0, 0, 0);
            }
        }
    }
    // ---- epilogue: merged[b][h*512 + q>>3][(q&7)*32 + d], bf16 ----
#pragma unroll
    for (int r = 0; r < 4; ++r) {
        float inv = 1.f / l_run[r];
        int q = qt * 64 + w * 16 + lg * 4 + r;
        size_t base = ((size_t)b * NTOK + h * 512 + (q >> 3)) * 256 + (q & 7) * 32;
#pragma unroll
        for (int dt = 0; dt < 2; ++dt)
            merged[base + dt * 16 + lc] = f2bf(oacc[dt][r] * inv);
    }
}

// ---------------- layernorm over 256, one wave per row ----------------
// OUT_BF16: write bf16 to dst; else fp32. HAS_RESID: add bf16 residual.
template <int OUT_BF16, int HAS_RESID>
__global__ __launch_bounds__(256) void ln_kernel(
    const float* __restrict__ src, int src_ld,
    const float* __restrict__ gamma, const float* __restrict__ beta,
    void* __restrict__ dst, int dst_ld, int dst_off,
    const unsigned short* __restrict__ resid, int resid_ld) {
    int lane = threadIdx.x & 63;
    int wv = threadIdx.x >> 6;
    int row = blockIdx.x * 4 + wv;
    const float* p = src + (size_t)row * src_ld;
    float4 v4 = *(const float4*)&p[lane * 4];
    float vv[4] = {v4.x, v4.y, v4.z, v4.w};
    float sum = vv[0] + vv[1] + vv[2] + vv[3];
#pragma unroll
    for (int off = 32; off >= 1; off >>= 1) sum += __shfl_xor(sum, off);
    float mu = sum * (1.f / 256.f);
    float vs = 0.f;
#pragma unroll
    for (int j = 0; j < 4; ++j) {
        float dxe = vv[j] - mu;
        vs += dxe * dxe;
    }
#pragma unroll
    for (int off = 32; off >= 1; off >>= 1) vs += __shfl_xor(vs, off);
    float rs = rsqrtf(vs * (1.f / 256.f) + 1e-5f);
#pragma unroll
    for (int j = 0; j < 4; ++j) {
        int c = lane * 4 + j;
        float val = (vv[j] - mu) * rs * gamma[c] + beta[c];
        if (HAS_RESID) val += bf2f(resid[(size_t)row * resid_ld + c]);
        if (OUT_BF16)
            ((unsigned short*)dst)[(size_t)row * dst_ld + dst_off + c] = f2bf(val);
        else
            ((float*)dst)[(size_t)row * dst_ld + dst_off + c] = val;
    }
}

extern "C" void kernel_launch(void* const* d_in, const int* in_sizes, int n_in,
                              void* d_out, int out_size, void* d_ws, size_t ws_size,
                              hipStream_t stream) {
    const float* x = (const float*)d_in[0];
    const float* source = (const float*)d_in[1];
    const float* Wq = (const float*)d_in[2];
    const float* bq = (const float*)d_in[3];
    const float* Wk = (const float*)d_in[4];
    const float* bk = (const float*)d_in[5];
    const float* Wv = (const float*)d_in[6];
    const float* bv = (const float*)d_in[7];
    const float* Wm = (const float*)d_in[8];
    const float* Wmlp1 = (const float*)d_in[9];
    const float* Wmlp2 = (const float*)d_in[10];
    const float* g1 = (const float*)d_in[11];
    const float* b1 = (const float*)d_in[12];
    const float* g2 = (const float*)d_in[13];
    const float* b2 = (const float*)d_in[14];
    float* out = (float*)d_out;
    unsigned short* u = (unsigned short*)d_ws;

    // workspace layout (ushort offsets):
    unsigned short* C0bf = u;                 // (2,4096,512) bf16: [:,:,0:256]=xt, [256:512]=a
    unsigned short* stbf = u + 4194304;       // (2,4096,256) bf16
    unsigned short* WqT  = u + 6291456;       // (256,256) bf16 each
    unsigned short* WkT  = u + 6356992;
    unsigned short* WvT  = u + 6422528;
    unsigned short* WmT  = u + 6488064;
    unsigned short* W1T  = u + 6553600;       // (512,512)
    unsigned short* W2T  = u + 6815744;       // (256,512)
    unsigned short* Qb   = u + 6946816;       // (2,8,4096,32) bf16
    unsigned short* Kb   = u + 9043968;
    unsigned short* Vt   = u + 11141120;      // (2,8,32,4096) bf16
    unsigned short* merged = u + 13238272;    // (2,4096,256) bf16
    float* t1 = (float*)(u + 6946816);        // fp32 (2,4096,256), reuses Qb+Kb after attn
    unsigned short* t2 = u + 11141120;        // bf16 (2,4096,512), reuses Vt+merged after Wm GEMM
    float* t3 = (float*)(u + 15335424);       // fp32 (2,4096,256)

    // 1. activations -> bf16 token-major
    transpose_bf_kernel<<<dim3(128, 8, B_SZ), 256, 0, stream>>>(x, C0bf, 256, 4096, 512);
    transpose_bf_kernel<<<dim3(128, 8, B_SZ), 256, 0, stream>>>(source, stbf, 256, 4096, 256);
    // 2. weights -> bf16 W^T
    transpose_bf_kernel<<<dim3(8, 8, 1), 256, 0, stream>>>(Wq, WqT, 256, 256, 256);
    transpose_bf_kernel<<<dim3(8, 8, 1), 256, 0, stream>>>(Wk, WkT, 256, 256, 256);
    transpose_bf_kernel<<<dim3(8, 8, 1), 256, 0, stream>>>(Wv, WvT, 256, 256, 256);
    transpose_bf_kernel<<<dim3(8, 8, 1), 256, 0, stream>>>(Wm, WmT, 256, 256, 256);
    transpose_bf_kernel<<<dim3(16, 16, 1), 256, 0, stream>>>(Wmlp1, W1T, 512, 512, 512);
    transpose_bf_kernel<<<dim3(8, 16, 1), 256, 0, stream>>>(Wmlp2, W2T, 512, 256, 512);

    // 3. Q/K/V projections (MFMA, bf16 out, head-major; V transposed)
    dim3 gqkv(128, 4);
    bgemm_kernel<0, 1><<<gqkv, 256, 0, stream>>>(C0bf, 512, WqT, bq, Qb, 0, 256);
    bgemm_kernel<0, 1><<<gqkv, 256, 0, stream>>>(stbf, 256, WkT, bk, Kb, 0, 256);
    bgemm_kernel<0, 2><<<gqkv, 256, 0, stream>>>(stbf, 256, WvT, bv, Vt, 0, 256);

    // 4. MFMA flash attention -> merged bf16 (head-flatten permute)
    attn_kernel<<<dim3(64, NH, B_SZ), 256, 0, stream>>>(Qb, Kb, Vt, merged);

    // 5. merged @ Wm -> t1 fp32
    bgemm_kernel<0, 0><<<gqkv, 256, 0, stream>>>(merged, 256, WmT, nullptr, t1, 256, 256);

    // 6. LN1 -> C0bf upper half (bf16)
    ln_kernel<1, 0><<<2048, 256, 0, stream>>>(t1, 256, g1, b1, C0bf, 512, 256, nullptr, 0);

    // 7. MLP1 + ReLU: C0bf (8192x512) @ W1T -> t2 bf16
    bgemm_kernel<1, 3><<<dim3(128, 8), 256, 0, stream>>>(C0bf, 512, W1T, nullptr, t2, 512, 512);

    // 8. MLP2: t2 @ W2T -> t3 fp32
    bgemm_kernel<0, 0><<<gqkv, 256, 0, stream>>>(t2, 512, W2T, nullptr, t3, 256, 512);

    // 9. LN2 + residual(xt bf16) -> out fp32
    ln_kernel<0, 1><<<2048, 256, 0, stream>>>(t3, 256, g2, b2, out, 256, 0, C0bf, 512);
}